// Round 5
// baseline (206.432 us; speedup 1.0000x reference)
//
#include <hip/hip_runtime.h>

// B=16, Q=2048, K=2048, D=128, DV=128
// out[b,q,:] = softmax_k((q.k - 0.5||k||^2)/sqrt(192), mask k>=valid_len) @ V
// R5: prep fused into attn kernel. Each block converts its own 64-key K/V
// slice (fp32 -> bf16 ws, V transposed) with coalesced loads + v_perm packing,
// then per-batch atomic release/acquire barrier (all 512 blocks co-resident:
// __launch_bounds__(256,2), grid=2/CU). Attn core identical to R4.

#define Bn   16
#define Qn   2048
#define Kn   2048
#define Dn   128
#define DVn  128
#define BQ   64
#define BK   64

// (1/sqrt(192)) * log2(e) : softmax computed as 2^(qk*SC2 + bias2)
#define SC2 0.10411754f

typedef short bf16x4 __attribute__((ext_vector_type(4)));
typedef short bf16x8 __attribute__((ext_vector_type(8)));
typedef float f32x16 __attribute__((ext_vector_type(16)));

__device__ __forceinline__ short f2bf(float x) {   // RNE (Q frags only)
    union { float f; unsigned u; } v; v.f = x;
    unsigned r = (v.u + 0x7fffu + ((v.u >> 16) & 1u)) >> 16;
    return (short)r;
}
// pack two floats -> two bf16 (round-half-up via +0x8000): [lo=a, hi=b]
__device__ __forceinline__ unsigned packbf(float a, float b) {
    return __builtin_amdgcn_perm(__float_as_uint(b) + 0x8000u,
                                 __float_as_uint(a) + 0x8000u, 0x07060302u);
}

typedef const __attribute__((address_space(1))) void* gas_t;
typedef __attribute__((address_space(3))) void* las_t;
__device__ __forceinline__ void gld16(const void* g, void* l) {
    __builtin_amdgcn_global_load_lds((gas_t)g, (las_t)l, 16, 0, 0);
}
__device__ __forceinline__ void gld4(const void* g, void* l) {
    __builtin_amdgcn_global_load_lds((gas_t)g, (las_t)l, 4, 0, 0);
}
__device__ __forceinline__ void barrier_lgkm() {
    asm volatile("s_waitcnt lgkmcnt(0)" ::: "memory");
    __builtin_amdgcn_s_barrier();
    asm volatile("" ::: "memory");
}
__device__ __forceinline__ float exp2_raw(float a) {  // D = 2^S0
    float p;
    asm("v_exp_f32 %0, %1" : "=v"(p) : "v"(a));
    return p;
}

__global__ __launch_bounds__(256, 2) void attn_kernel(
    const float* __restrict__ Qg, const float* __restrict__ Kg,
    const float* __restrict__ Vg, const int* __restrict__ VL,
    float* __restrict__ Og,
    short* __restrict__ Kb, short* __restrict__ Vtb,
    float* __restrict__ biasg, unsigned* __restrict__ cnt)
{
    __shared__ __align__(16) short Ksh[2][64 * 128];   // 32768 B
    __shared__ __align__(16) short Vsh[2][128 * 64];   // 32768 B
    __shared__ __align__(16) short Psh[2][32 * 64];    //  8192 B (swizzled, per-pair)
    __shared__ __align__(16) float biasSh[2][64];      //   512 B
    __shared__ float Lsum[4][32];                      //   512 B -> total 74752 B

    const int tid  = threadIdx.x;
    const int lane = tid & 63;
    const int w    = tid >> 6;    // wave 0..3
    const int pair = w >> 1;      // q-strip: rows [pair*32, pair*32+32)
    const int half = w & 1;       // key-half for S, v-half for PV
    const int l31  = lane & 31;
    const int hi   = lane >> 5;

    const int lin  = blockIdx.x;          // 0..511 ; XCD swizzle
    const int slot = lin >> 3;
    const int b    = (lin & 7) * 2 + (slot >> 5);
    const int s    = slot & 31;           // q-slot AND this block's prep tile
    const int q0   = s * BQ;

    const short* Kb_b = Kb  + (size_t)b * Kn * Dn;
    const short* Vt_b = Vtb + (size_t)b * DVn * Kn;
    const float* bias_b = biasg + b * Kn;

    // ================= PHASE A: prep this block's 64-key slice =================
    {   // ---- K slice: rows [s*64, s*64+64), 4 threads/row x 32 floats ----
        const int row = s * 64 + (tid >> 2);
        const int c   = (tid & 3) * 32;
        const float* src = Kg + ((size_t)b * Kn + row) * Dn + c;
        unsigned* dst = (unsigned*)(Kb + ((size_t)b * Kn + row) * Dn + c);
        float ssq = 0.f;
#pragma unroll
        for (int j = 0; j < 4; ++j) {
            float4 x0 = *(const float4*)(src + j * 8);
            float4 x1 = *(const float4*)(src + j * 8 + 4);
            ssq += x0.x*x0.x + x0.y*x0.y + x0.z*x0.z + x0.w*x0.w
                 + x1.x*x1.x + x1.y*x1.y + x1.z*x1.z + x1.w*x1.w;
            uint4 d;
            d.x = packbf(x0.x, x0.y); d.y = packbf(x0.z, x0.w);
            d.z = packbf(x1.x, x1.y); d.w = packbf(x1.z, x1.w);
            *(uint4*)(dst + j * 4) = d;
        }
        ssq += __shfl_xor(ssq, 1);
        ssq += __shfl_xor(ssq, 2);
        if ((tid & 3) == 0) biasg[b * Kn + row] = -0.5f * ssq * SC2;
    }
    {   // ---- V slice: 64k x 128v -> Vt[v][k], 8k x 4v per thread ----
        const int v0 = (tid & 31) * 4;
        const int ks = (tid >> 5) * 8;
        const float* src = Vg + ((size_t)b * Kn + s * 64 + ks) * DVn + v0;
        float4 rows[8];
#pragma unroll
        for (int j = 0; j < 8; ++j)
            rows[j] = *(const float4*)(src + (size_t)j * DVn);
#pragma unroll
        for (int vi = 0; vi < 4; ++vi) {
            const float* r0 = (const float*)&rows[0];
            uint4 d;
            d.x = packbf(((const float*)&rows[0])[vi], ((const float*)&rows[1])[vi]);
            d.y = packbf(((const float*)&rows[2])[vi], ((const float*)&rows[3])[vi]);
            d.z = packbf(((const float*)&rows[4])[vi], ((const float*)&rows[5])[vi]);
            d.w = packbf(((const float*)&rows[6])[vi], ((const float*)&rows[7])[vi]);
            *(uint4*)(Vtb + ((size_t)b * DVn + v0 + vi) * Kn + s * 64 + ks) = d;
        }
    }

    // ---- release: this block's slice is ready ----
    __syncthreads();
    unsigned* cntb = cnt + b * 16;   // 64B-spread counters
    if (tid == 0) {
        __threadfence();
        __hip_atomic_fetch_add(cntb, 1u, __ATOMIC_RELEASE, __HIP_MEMORY_SCOPE_AGENT);
    }

    // ================= overlap: Q fragments + valid_len (inputs only) ==========
    bf16x8 qf[8];
    {
        const float* qrow = Qg + ((size_t)b * Qn + q0 + pair * 32 + l31) * Dn;
#pragma unroll
        for (int kt = 0; kt < 8; ++kt) {
            const float* p = qrow + kt * 16 + hi * 8;
            float4 x0 = *(const float4*)(p);
            float4 x1 = *(const float4*)(p + 4);
            bf16x8 f;
            f[0]=f2bf(x0.x); f[1]=f2bf(x0.y); f[2]=f2bf(x0.z); f[3]=f2bf(x0.w);
            f[4]=f2bf(x1.x); f[5]=f2bf(x1.y); f[6]=f2bf(x1.z); f[7]=f2bf(x1.w);
            qf[kt] = f;
        }
    }
    const int vlq = VL[b * Qn + q0 + pair * 32 + l31];

    // ---- acquire: wait for all 32 producers of batch b ----
    if (tid == 0) {
        int spins = 0;
        while (__hip_atomic_load(cntb, __ATOMIC_ACQUIRE, __HIP_MEMORY_SCOPE_AGENT) < 32u) {
            if (++spins > (1 << 16)) break;   // hang guard (~30 ms)
            __builtin_amdgcn_s_sleep(16);
        }
    }
    __syncthreads();

    // ================= PHASE B: attention (R4 core) ============================
    const short* ksp[4]; int kdo[4];
    const short* vsp[4]; int vdo[4];
#pragma unroll
    for (int i = 0; i < 4; ++i) {
        const int rl = w * 16 + i * 4 + (lane >> 4);       // K tile row 0..63
        const int ch = (lane & 15) ^ (rl & 15);
        ksp[i] = Kb_b + (size_t)rl * Dn + ch * 8;
        kdo[i] = (w * 16 + i * 4) * 128;
        const int rv = w * 32 + i * 8 + (lane >> 3);       // V tile row 0..127
        const int cv = (lane & 7) ^ (rv & 7);
        vsp[i] = Vt_b + (size_t)rv * Kn + cv * 8;
        vdo[i] = (w * 32 + i * 8) * 64;
    }

    f32x16 Oacc[2];
#pragma unroll
    for (int nt = 0; nt < 2; ++nt)
#pragma unroll
        for (int j = 0; j < 16; ++j) Oacc[nt][j] = 0.f;
    float psum = 0.f;

    // prologue: DMA tile 0 into buffer 0
#pragma unroll
    for (int i = 0; i < 4; ++i) {
        gld16(ksp[i], &Ksh[0][kdo[i]]);
        gld16(vsp[i], &Vsh[0][vdo[i]]);
    }
    if (w == 0) gld4(bias_b + lane, &biasSh[0][0]);

    const int swl = (l31 & 7) << 1;   // P-strip swizzle key (pair-preserving)

    for (int k0k = 0; k0k < Kn; k0k += BK) {
        const int buf = (k0k >> 6) & 1;
        __syncthreads();   // drains vmcnt(0): tile ready; prev readers done

        if (k0k + BK < Kn) {
            const int nk = k0k + BK;
#pragma unroll
            for (int i = 0; i < 4; ++i) {
                gld16(ksp[i] + (size_t)nk * Dn, &Ksh[buf ^ 1][kdo[i]]);
                gld16(vsp[i] + nk,              &Vsh[buf ^ 1][vdo[i]]);
            }
            if (w == 0) gld4(bias_b + nk + lane, &biasSh[buf ^ 1][0]);
        }

        float4 bv[4];
#pragma unroll
        for (int rq = 0; rq < 4; ++rq)
            bv[rq] = *(const float4*)&biasSh[buf][half * 32 + rq * 8 + hi * 4];

        // ---- S^T = K_half . Q^T : one 32x32 tile per wave (8 MFMA) ----
        const short* kbuf = Ksh[buf];
        const int kr = half * 32 + l31;
        f32x16 Sv;
#pragma unroll
        for (int j = 0; j < 16; ++j) Sv[j] = 0.f;
#pragma unroll
        for (int kt = 0; kt < 8; ++kt) {
            bf16x8 kf = *(const bf16x8*)&kbuf[kr * 128 + (((kt*2 + hi) ^ (kr & 15)) * 8)];
            Sv = __builtin_amdgcn_mfma_f32_32x32x16_bf16(kf, qf[kt], Sv, 0, 0, 0);
        }

        // ---- softmax in exp2 domain ----
        float pv[16];
#pragma unroll
        for (int rq = 0; rq < 4; ++rq) {
#pragma unroll
            for (int r = 0; r < 4; ++r) {
                const int reg = rq * 4 + r;
                const int keyg = k0k + half * 32 + rq * 8 + hi * 4 + r;
                float a = fmaf(Sv[reg], SC2, bv[rq][r]);
                a = (keyg < vlq) ? a : -200.0f;
                const float p = exp2_raw(a);
                psum += p;
                pv[reg] = p;
            }
        }

        // ---- pack + swizzled b64 writes ----
        short* pp = &Psh[pair][0];
#pragma unroll
        for (int rq = 0; rq < 4; ++rq) {
            uint2 d;
            d.x = __builtin_amdgcn_perm(__float_as_uint(pv[rq*4+1]),
                                        __float_as_uint(pv[rq*4+0]), 0x07060302u);
            d.y = __builtin_amdgcn_perm(__float_as_uint(pv[rq*4+3]),
                                        __float_as_uint(pv[rq*4+2]), 0x07060302u);
            const int g  = half * 8 + rq * 2 + hi;
            const int gp = g ^ swl;
            *(uint2*)&pp[l31 * 64 + gp * 4] = d;
        }
        barrier_lgkm();   // P visible pair-wide; DMA stays in flight

        // ---- O += P @ V ----
        const short* vbuf = Vsh[buf];
#pragma unroll
        for (int kt = 0; kt < 4; ++kt) {
            bf16x8 pf = *(const bf16x8*)&pp[l31 * 64 + (((kt*2 + hi) ^ (l31 & 7)) * 8)];
#pragma unroll
            for (int nt = 0; nt < 2; ++nt) {
                const int v = half * 64 + nt * 32 + l31;
                bf16x8 vf = *(const bf16x8*)&vbuf[v * 64 + (((kt*2 + hi) ^ (v & 7)) * 8)];
                Oacc[nt] = __builtin_amdgcn_mfma_f32_32x32x16_bf16(pf, vf, Oacc[nt], 0, 0, 0);
            }
        }
    }

    // ---- epilogue ----
    psum += __shfl_xor(psum, 32);
    if (lane < 32) Lsum[w][l31] = psum;
    __syncthreads();

    float invl[16];
#pragma unroll
    for (int rq = 0; rq < 4; ++rq)
#pragma unroll
        for (int r = 0; r < 4; ++r) {
            const int ql = r + 8 * rq + 4 * hi;
            invl[rq*4+r] = 1.f / (Lsum[pair*2][ql] + Lsum[pair*2+1][ql]);
        }
    float* obase = Og + ((size_t)b * Qn + q0 + pair * 32) * DVn;
#pragma unroll
    for (int nt = 0; nt < 2; ++nt)
#pragma unroll
        for (int rq = 0; rq < 4; ++rq)
#pragma unroll
            for (int r = 0; r < 4; ++r) {
                const int row = r + 8 * rq + 4 * hi;
                const int col = half * 64 + nt * 32 + l31;
                obase[(size_t)row * DVn + col] = Oacc[nt][rq*4+r] * invl[rq*4+r];
            }
}

extern "C" void kernel_launch(void* const* d_in, const int* in_sizes, int n_in,
                              void* d_out, int out_size, void* d_ws, size_t ws_size,
                              hipStream_t stream) {
    const float* Qg = (const float*)d_in[0];
    const float* Kg = (const float*)d_in[1];
    const float* Vg = (const float*)d_in[2];
    const int*   VL = (const int*)d_in[3];
    float* Og = (float*)d_out;

    // ws: Kb bf16 (8MB) | Vtb bf16 (8MB) | bias2 f32 (128KB) | counters (1KB)
    char* ws = (char*)d_ws;
    short*    Kb   = (short*)(ws);
    short*    Vtb  = (short*)(ws + (size_t)Bn * Kn * Dn * 2);
    float*    bias = (float*)(ws + (size_t)Bn * Kn * Dn * 4);
    unsigned* cnt  = (unsigned*)(ws + (size_t)Bn * Kn * Dn * 4 + (size_t)Bn * Kn * 4);

    hipMemsetAsync(cnt, 0, Bn * 16 * sizeof(unsigned), stream);
    attn_kernel<<<dim3(512), dim3(256), 0, stream>>>(Qg, Kg, Vg, VL, Og,
                                                     Kb, Vtb, bias, cnt);
}